// Round 1
// baseline (61.093 us; speedup 1.0000x reference)
//
#include <hip/hip_runtime.h>

// Problem constants (fixed by the reference)
#define B_DIM      8
#define N_ATOMS    64
#define NUM_CH     5
#define GRID_DIM   32
#define CROP_LO    70          // c - 16 where c = 173/2 = 86
#define CROP_HI    101         // inclusive
#define CUBES      5
#define LATO       11
#define KCELLS     (LATO*LATO*LATO)   // 1331

__global__ __launch_bounds__(256) void zero_out_kernel(float4* __restrict__ out, int n4) {
    int i = blockIdx.x * blockDim.x + threadIdx.x;
    if (i < n4) out[i] = make_float4(0.f, 0.f, 0.f, 0.f);
}

__global__ __launch_bounds__(256) void splat_kernel(
    const float* __restrict__ coords,     // [B, N, 3]
    const int*   __restrict__ channel,    // [B, N]
    const float* __restrict__ radius,     // [B, N]
    float* __restrict__ out)              // [B, NUM_CH, 32, 32, 32]
{
    const int atom = blockIdx.x;                    // 0 .. B*N-1
    const int b    = atom >> 6;                     // N_ATOMS == 64

    // scaled = (c + 20)/0.25 + 6 = c*4 + 86
    const float sx = coords[3*atom + 0] * 4.0f + 86.0f;
    const float sy = coords[3*atom + 1] * 4.0f + 86.0f;
    const float sz = coords[3*atom + 2] * 4.0f + 86.0f;
    const int bx = (int)floorf(sx);
    const int by = (int)floorf(sy);
    const int bz = (int)floorf(sz);

    // Early out: whole 11^3 window misses the crop in some dimension.
    if (bx + CUBES < CROP_LO || bx - CUBES > CROP_HI ||
        by + CUBES < CROP_LO || by - CUBES > CROP_HI ||
        bz + CUBES < CROP_LO || bz - CUBES > CROP_HI) return;

    const float r  = radius[atom];
    // val = exp(-0.5 * d2_A2 / r^2), d2_A2 = d2_voxels * RES^2 = d2_voxels * 0.0625
    const float karg = -0.5f * 0.0625f / (r * r);
    const int ch = channel[atom];
    float* outBase = out + ((size_t)(b * NUM_CH + ch)) * (GRID_DIM*GRID_DIM*GRID_DIM);

    for (int k = threadIdx.x; k < KCELLS; k += 256) {
        const int i   = k / (LATO*LATO);            // constant divide -> magic mul
        const int rem = k - i * (LATO*LATO);
        const int j   = rem / LATO;
        const int l   = rem - j * LATO;

        const int gx = bx - CUBES + i;
        const int gy = by - CUBES + j;
        const int gz = bz - CUBES + l;

        const unsigned ux = (unsigned)(gx - CROP_LO);
        const unsigned uy = (unsigned)(gy - CROP_LO);
        const unsigned uz = (unsigned)(gz - CROP_LO);
        if (ux < GRID_DIM && uy < GRID_DIM && uz < GRID_DIM) {
            const float dx = sx - ((float)gx + 0.5f);
            const float dy = sy - ((float)gy + 0.5f);
            const float dz = sz - ((float)gz + 0.5f);
            const float d2 = dx*dx + dy*dy + dz*dz;
            const float val = __expf(d2 * karg);
            atomicAdd(outBase + ((ux * GRID_DIM) + uy) * GRID_DIM + uz, val);
        }
    }
}

extern "C" void kernel_launch(void* const* d_in, const int* in_sizes, int n_in,
                              void* d_out, int out_size, void* d_ws, size_t ws_size,
                              hipStream_t stream) {
    const float* coords  = (const float*)d_in[0];
    const int*   channel = (const int*)d_in[1];
    const float* radius  = (const float*)d_in[2];
    float* out = (float*)d_out;

    // Zero the output (harness poisons it with 0xAA before every launch).
    const int n4 = out_size / 4;   // out_size = 8*5*32^3 = 1310720, divisible by 4
    hipLaunchKernelGGL(zero_out_kernel, dim3((n4 + 255) / 256), dim3(256), 0, stream,
                       (float4*)out, n4);

    // One block per atom (dumb atoms never touch the crop; they aren't in d_in anyway).
    const int atoms = in_sizes[1]; // B*N = 512
    hipLaunchKernelGGL(splat_kernel, dim3(atoms), dim3(256), 0, stream,
                       coords, channel, radius, out);
}